// Round 1
// 71.812 us; speedup vs baseline: 1.0039x; 1.0039x over previous
//
#include <hip/hip_runtime.h>

#define DD 128   // feature dim
#define SR 72    // LDS row stride in bf16 units (64 + 8 pad, bank-spread)
#define PP 128   // partial tiles per matrix
#define NB (2*PP)

typedef float f32x4 __attribute__((ext_vector_type(4)));
typedef short s16x8 __attribute__((ext_vector_type(8)));

// ---------------------------------------------------------------------------
// MAXIMALLY DEFENSIVE STRUCTURE: three dispatches, NO atomics, NO fences,
// NO cross-block communication. All inter-block data flow crosses a
// stream-ordered kernel boundary.
//
// Dispatch 1: per-block partial Gram tiles A_p = Xslab^T Xslab (blk<PP) or
// B_p = Yslab^T Yslab via bf16 hi/lo-split MFMA (G = Xh'Xh + Xh'Xl + Xl'Xh,
// ll dropped, ~2^-15 relative). 64-row slab staged TRANSPOSED in LDS.
// X-blocks fold diag sums s1 = sum<x_i,y_i>, s2 = sum<..>^2 from the
// original fp32 registers -> plain stores into per-block slots (no memset).
//
// R11 change: partial tiles are stored in a PERMUTED-LINEAR layout
// (dst4[t*512 + tid] = acc[t]) — dot_kernel only needs apart/bpart in the
// SAME element order, not row-major, so the epilogue becomes 8 fully
// coalesced dwordx4 stores/thread instead of 32 strided scalar stores.
// ---------------------------------------------------------------------------
__global__ __launch_bounds__(512)
void gram_kernel(const float* __restrict__ x, const float* __restrict__ y,
                 float* __restrict__ apart, float* __restrict__ bpart,
                 double* __restrict__ ds1, double* __restrict__ ds2, int N)
{
  const int blk = blockIdx.x;
  const bool isX = blk < PP;
  const int p = isX ? blk : blk - PP;
  const float* __restrict__ src = isX ? x : y;
  const int slab = N / PP;       // 64
  const int row0 = p * slab;

  __shared__ __align__(16) unsigned short sh_hi[DD * SR];  // 18.4 KB
  __shared__ __align__(16) unsigned short sh_lo[DD * SR];  // 18.4 KB
  __shared__ double wred[8][2];

  const int tid = threadIdx.x;
  const int wave = tid >> 6, lane = tid & 63;
  const int rloc = tid >> 3;     // row within 64-row chunk
  const int fg = tid & 7;        // float4 group within row

  f32x4 acc[8];
#pragma unroll
  for (int t = 0; t < 8; ++t)
#pragma unroll
    for (int k = 0; k < 4; ++k) acc[t][k] = 0.f;

  double s1 = 0.0, s2 = 0.0;

  {
    const float* cb = src + (size_t)row0 * DD;
    const float4* rowp = (const float4*)(cb + rloc * DD);
    float4 v0 = rowp[fg], v1 = rowp[fg + 8], v2 = rowp[fg + 16], v3 = rowp[fg + 24];

    if (isX) {
      const float4* yrp = (const float4*)(y + (size_t)row0 * DD + rloc * DD);
      float4 w0 = yrp[fg], w1 = yrp[fg + 8], w2 = yrp[fg + 16], w3 = yrp[fg + 24];
      float d = v0.x*w0.x + v0.y*w0.y + v0.z*w0.z + v0.w*w0.w
              + v1.x*w1.x + v1.y*w1.y + v1.z*w1.z + v1.w*w1.w
              + v2.x*w2.x + v2.y*w2.y + v2.z*w2.z + v2.w*w2.w
              + v3.x*w3.x + v3.y*w3.y + v3.z*w3.z + v3.w*w3.w;
      d += __shfl_down(d, 4, 8);
      d += __shfl_down(d, 2, 8);
      d += __shfl_down(d, 1, 8);
      if (fg == 0) { s1 += (double)d; s2 += (double)d * (double)d; }
    }

    {
      float vals[16] = {v0.x, v0.y, v0.z, v0.w, v1.x, v1.y, v1.z, v1.w,
                        v2.x, v2.y, v2.z, v2.w, v3.x, v3.y, v3.z, v3.w};
#pragma unroll
      for (int j = 0; j < 4; ++j)
#pragma unroll
        for (int cc = 0; cc < 4; ++cc) {
          const int m = ((fg + (j << 3)) << 2) + cc;
          const float vv = vals[j * 4 + cc];
          const unsigned int b = __float_as_uint(vv);
          const unsigned short hb = (unsigned short)(b >> 16);
          const float hf = __uint_as_float(b & 0xffff0000u);
          const float lf = vv - hf;
          const unsigned short lb = (unsigned short)(__float_as_uint(lf) >> 16);
          sh_hi[m * SR + rloc] = hb;
          sh_lo[m * SR + rloc] = lb;
        }
    }
    __syncthreads();

#pragma unroll
    for (int kb = 0; kb < 64; kb += 32) {
      const int ko = kb + ((lane >> 4) << 3);
      const int arow = (wave * 16 + (lane & 15)) * SR + ko;
      const s16x8 ahi = *(const s16x8*)&sh_hi[arow];
      const s16x8 alo = *(const s16x8*)&sh_lo[arow];
#pragma unroll
      for (int t = 0; t < 8; ++t) {
        const int brow = (t * 16 + (lane & 15)) * SR + ko;
        const s16x8 bhi = *(const s16x8*)&sh_hi[brow];
        const s16x8 blo = *(const s16x8*)&sh_lo[brow];
        acc[t] = __builtin_amdgcn_mfma_f32_16x16x32_bf16(ahi, bhi, acc[t], 0, 0, 0);
        acc[t] = __builtin_amdgcn_mfma_f32_16x16x32_bf16(ahi, blo, acc[t], 0, 0, 0);
        acc[t] = __builtin_amdgcn_mfma_f32_16x16x32_bf16(alo, bhi, acc[t], 0, 0, 0);
      }
    }
  }

  // write private partial tile in PERMUTED-LINEAR layout: element order is
  // irrelevant downstream (dot_kernel applies the same permutation to apart
  // and bpart), so store each f32x4 accumulator as one coalesced dwordx4.
  f32x4* __restrict__ dst4 = (f32x4*)((isX ? apart : bpart) + (size_t)p * (DD * DD));
#pragma unroll
  for (int t = 0; t < 8; ++t)
    dst4[t * 512 + tid] = acc[t];

  if (isX) {
    // diag partials live on lanes 0,8,...,56 of each wave
    s1 += __shfl_down(s1, 32, 64); s2 += __shfl_down(s2, 32, 64);
    s1 += __shfl_down(s1, 16, 64); s2 += __shfl_down(s2, 16, 64);
    s1 += __shfl_down(s1, 8, 64);  s2 += __shfl_down(s2, 8, 64);
    if (lane == 0) { wred[wave][0] = s1; wred[wave][1] = s2; }
    __syncthreads();
    if (tid == 0) {
      double t1 = 0.0, t2 = 0.0;
#pragma unroll
      for (int g = 0; g < 8; ++g) { t1 += wred[g][0]; t2 += wred[g][1]; }
      ds1[p] = t1;   // plain stores, no init required
      ds2[p] = t2;
    }
  }
}

// ---------------------------------------------------------------------------
// Dispatch 2: per-block partial dot, float4 granularity. Block owns 16
// float4 slots (64 elements); thread (s = tid&15, pg = tid>>4) sums partials
// p = pg + 16*i (4 independent p-streams in flight per wave). LDS combine
// over the 16 p-groups, 16-wide shuffle reduce -> prod[blk] plain store.
// No atomics, no finish here.
// ---------------------------------------------------------------------------
__global__ __launch_bounds__(256)
void dot_kernel(const float* __restrict__ apart, const float* __restrict__ bpart,
                double* __restrict__ prod)
{
  const int tid = threadIdx.x;
  const int s = tid & 15;          // float4 slot within this block's 16
  const int pg = tid >> 4;         // p-group 0..15
  const f32x4* __restrict__ a4 = (const f32x4*)apart;
  const f32x4* __restrict__ b4 = (const f32x4*)bpart;
  const int base = blockIdx.x * 16 + s;   // float4 index within a partial tile

  f32x4 sa = {0.f, 0.f, 0.f, 0.f}, sb = {0.f, 0.f, 0.f, 0.f};
#pragma unroll
  for (int i = 0; i < 8; ++i) {
    const int p = pg + (i << 4);
    sa += a4[(size_t)p * (DD * DD / 4) + base];
    sb += b4[(size_t)p * (DD * DD / 4) + base];
  }

  __shared__ f32x4 sA[16][16], sB[16][16];
  sA[pg][s] = sa;
  sB[pg][s] = sb;
  __syncthreads();

  if (tid < 16) {
    f32x4 ta = sA[0][tid], tb = sB[0][tid];
#pragma unroll
    for (int g = 1; g < 16; ++g) { ta += sA[g][tid]; tb += sB[g][tid]; }
    double pr = (double)ta[0] * (double)tb[0]
              + (double)ta[1] * (double)tb[1]
              + (double)ta[2] * (double)tb[2]
              + (double)ta[3] * (double)tb[3];
    pr += __shfl_down(pr, 8, 16);
    pr += __shfl_down(pr, 4, 16);
    pr += __shfl_down(pr, 2, 16);
    pr += __shfl_down(pr, 1, 16);
    if (tid == 0) prod[blockIdx.x] = pr;   // plain store
  }
}

// ---------------------------------------------------------------------------
// Dispatch 3: one block reduces 256 prods + 128 ds1/ds2 slots (double) and
// writes loss = (S - s2)/(N(N-1)) - (2/N)*s1.
// ---------------------------------------------------------------------------
__global__ __launch_bounds__(256)
void finish_kernel(const double* __restrict__ prod,
                   const double* __restrict__ ds1, const double* __restrict__ ds2,
                   float* __restrict__ out, int N)
{
  const int tid = threadIdx.x;
  const int wv = tid >> 6, lane = tid & 63;
  __shared__ double red[4][3];

  double S = prod[tid];                       // 256 entries
  double t1 = (tid < PP) ? ds1[tid] : 0.0;    // 128 entries
  double t2 = (tid < PP) ? ds2[tid] : 0.0;
#pragma unroll
  for (int off = 32; off > 0; off >>= 1) {
    S  += __shfl_down(S, off, 64);
    t1 += __shfl_down(t1, off, 64);
    t2 += __shfl_down(t2, off, 64);
  }
  if (lane == 0) { red[wv][0] = S; red[wv][1] = t1; red[wv][2] = t2; }
  __syncthreads();
  if (tid == 0) {
    double Sf = red[0][0] + red[1][0] + red[2][0] + red[3][0];
    double d1 = red[0][1] + red[1][1] + red[2][1] + red[3][1];
    double d2 = red[0][2] + red[1][2] + red[2][2] + red[3][2];
    double loss = (Sf - d2) / ((double)N * (double)(N - 1)) - (2.0 / N) * d1;
    out[0] = (float)loss;
  }
}

extern "C" void kernel_launch(void* const* d_in, const int* in_sizes, int n_in,
                              void* d_out, int out_size, void* d_ws, size_t ws_size,
                              hipStream_t stream) {
  const float* x = (const float*)d_in[0];
  const float* y = (const float*)d_in[1];
  float* out = (float*)d_out;
  const int N = in_sizes[0] / DD;  // 8192

  char* w = (char*)d_ws;
  float* apart = (float*)w;                              w += (size_t)PP * DD * DD * 4;
  float* bpart = (float*)w;                              w += (size_t)PP * DD * DD * 4;
  double* ds1  = (double*)w;                             w += PP * 8;
  double* ds2  = (double*)w;                             w += PP * 8;
  double* prod = (double*)w;

  gram_kernel<<<NB, 512, 0, stream>>>(x, y, apart, bpart, ds1, ds2, N);
  dot_kernel<<<(DD * DD) / 64, 256, 0, stream>>>(apart, bpart, prod);
  finish_kernel<<<1, 256, 0, stream>>>(prod, ds1, ds2, out, N);
}

// Round 2
// 68.982 us; speedup vs baseline: 1.0451x; 1.0410x over previous
//
#include <hip/hip_runtime.h>

#define DD 128   // feature dim
#define SR 72    // LDS row stride in bf16 units (64 + 8 pad, bank-spread)
#define PP 128   // partial tiles per matrix
#define NB (2*PP)
#define NT 36    // upper-triangle 16x16 sub-tiles per partial (8*9/2)

typedef float f32x4 __attribute__((ext_vector_type(4)));
typedef short s16x8 __attribute__((ext_vector_type(8)));

// ---------------------------------------------------------------------------
// Three dispatches, NO atomics, NO fences, NO cross-block communication.
//
// R12 change: exploit symmetry. S = tr(Gx*Gy) = <Gx,Gy>_F with Gx,Gy
// symmetric; each per-block partial Z'Z is symmetric (hi/lo split
// Zh'Zh + Zh'Zl + Zl'Zh is symmetric as a sum). So gram computes/stores only
// the NT=36 upper-triangle 16x16 sub-tiles (packed, element order irrelevant
// but consistent between apart/bpart), statically rebalanced 4-5 per wave.
// dot weights off-diagonal sub-tiles by 2.0 (exact). Write traffic 16->9 MiB,
// MFMA -40%, dot read 16->9 MiB, same 256-block parallelism.
// ---------------------------------------------------------------------------
__global__ __launch_bounds__(512)
void gram_kernel(const float* __restrict__ x, const float* __restrict__ y,
                 float* __restrict__ apart, float* __restrict__ bpart,
                 double* __restrict__ ds1, double* __restrict__ ds2, int N)
{
  const int blk = blockIdx.x;
  const bool isX = blk < PP;
  const int p = isX ? blk : blk - PP;
  const float* __restrict__ src = isX ? x : y;
  const int slab = N / PP;       // 64
  const int row0 = p * slab;

  __shared__ __align__(16) unsigned short sh_hi[DD * SR];  // 18.4 KB
  __shared__ __align__(16) unsigned short sh_lo[DD * SR];  // 18.4 KB
  __shared__ double wred[8][2];

  const int tid = threadIdx.x;
  const int wave = tid >> 6, lane = tid & 63;
  const int rloc = tid >> 3;     // row within 64-row chunk
  const int fg = tid & 7;        // float4 group within row

  // static upper-triangle tile list, rebalanced: wave w owns tiles
  // [start, start+cnt) of the packed (r<=c) enumeration; 4 or 5 each.
  const int start = (9 * wave) >> 1;          // {0,4,9,13,18,22,27,31}
  const int cnt = 4 + (wave & 1);             // {4,5,4,5,4,5,4,5}
  int tr_[5], tc_[5];
#pragma unroll
  for (int j = 0; j < 5; ++j) {
    const int tile = start + j;
    int r = 0;
#pragma unroll
    for (int q = 1; q < 8; ++q) r += (tile >= ((q * (17 - q)) >> 1)) ? 1 : 0;
    tr_[j] = r;
    tc_[j] = tile - ((r * (17 - r)) >> 1) + r;  // c = r + (tile - rowstart(r))
  }

  f32x4 acc[5];
#pragma unroll
  for (int t = 0; t < 5; ++t)
#pragma unroll
    for (int k = 0; k < 4; ++k) acc[t][k] = 0.f;

  double s1 = 0.0, s2 = 0.0;

  {
    const float* cb = src + (size_t)row0 * DD;
    const float4* rowp = (const float4*)(cb + rloc * DD);
    float4 v0 = rowp[fg], v1 = rowp[fg + 8], v2 = rowp[fg + 16], v3 = rowp[fg + 24];

    if (isX) {
      const float4* yrp = (const float4*)(y + (size_t)row0 * DD + rloc * DD);
      float4 w0 = yrp[fg], w1 = yrp[fg + 8], w2 = yrp[fg + 16], w3 = yrp[fg + 24];
      float d = v0.x*w0.x + v0.y*w0.y + v0.z*w0.z + v0.w*w0.w
              + v1.x*w1.x + v1.y*w1.y + v1.z*w1.z + v1.w*w1.w
              + v2.x*w2.x + v2.y*w2.y + v2.z*w2.z + v2.w*w2.w
              + v3.x*w3.x + v3.y*w3.y + v3.z*w3.z + v3.w*w3.w;
      d += __shfl_down(d, 4, 8);
      d += __shfl_down(d, 2, 8);
      d += __shfl_down(d, 1, 8);
      if (fg == 0) { s1 += (double)d; s2 += (double)d * (double)d; }
    }

    {
      float vals[16] = {v0.x, v0.y, v0.z, v0.w, v1.x, v1.y, v1.z, v1.w,
                        v2.x, v2.y, v2.z, v2.w, v3.x, v3.y, v3.z, v3.w};
#pragma unroll
      for (int j = 0; j < 4; ++j)
#pragma unroll
        for (int cc = 0; cc < 4; ++cc) {
          const int m = ((fg + (j << 3)) << 2) + cc;
          const float vv = vals[j * 4 + cc];
          const unsigned int b = __float_as_uint(vv);
          const unsigned short hb = (unsigned short)(b >> 16);
          const float hf = __uint_as_float(b & 0xffff0000u);
          const float lf = vv - hf;
          const unsigned short lb = (unsigned short)(__float_as_uint(lf) >> 16);
          sh_hi[m * SR + rloc] = hb;
          sh_lo[m * SR + rloc] = lb;
        }
    }
    __syncthreads();

#pragma unroll
    for (int j = 0; j < 5; ++j) {
      if (j < cnt) {
        const int ar0 = (tr_[j] * 16 + (lane & 15)) * SR;
        const int br0 = (tc_[j] * 16 + (lane & 15)) * SR;
#pragma unroll
        for (int kb = 0; kb < 64; kb += 32) {
          const int ko = kb + ((lane >> 4) << 3);
          const s16x8 ahi = *(const s16x8*)&sh_hi[ar0 + ko];
          const s16x8 alo = *(const s16x8*)&sh_lo[ar0 + ko];
          const s16x8 bhi = *(const s16x8*)&sh_hi[br0 + ko];
          const s16x8 blo = *(const s16x8*)&sh_lo[br0 + ko];
          acc[j] = __builtin_amdgcn_mfma_f32_16x16x32_bf16(ahi, bhi, acc[j], 0, 0, 0);
          acc[j] = __builtin_amdgcn_mfma_f32_16x16x32_bf16(ahi, blo, acc[j], 0, 0, 0);
          acc[j] = __builtin_amdgcn_mfma_f32_16x16x32_bf16(alo, bhi, acc[j], 0, 0, 0);
        }
      }
    }
  }

  // packed upper-triangle store: tile t occupies f32x4 slots [t*64, t*64+64),
  // one coalesced dwordx4 per lane per tile. Element order within a tile is
  // the MFMA lane order — identical for apart and bpart, which is all the
  // elementwise dot needs.
  f32x4* __restrict__ dst4 = (f32x4*)(isX ? apart : bpart) + (size_t)p * (NT * 64);
#pragma unroll
  for (int j = 0; j < 5; ++j)
    if (j < cnt) dst4[(start + j) * 64 + lane] = acc[j];

  if (isX) {
    // diag partials live on lanes 0,8,...,56 of each wave
    s1 += __shfl_down(s1, 32, 64); s2 += __shfl_down(s2, 32, 64);
    s1 += __shfl_down(s1, 16, 64); s2 += __shfl_down(s2, 16, 64);
    s1 += __shfl_down(s1, 8, 64);  s2 += __shfl_down(s2, 8, 64);
    if (lane == 0) { wred[wave][0] = s1; wred[wave][1] = s2; }
    __syncthreads();
    if (tid == 0) {
      double t1 = 0.0, t2 = 0.0;
#pragma unroll
      for (int g = 0; g < 8; ++g) { t1 += wred[g][0]; t2 += wred[g][1]; }
      ds1[p] = t1;   // plain stores, no init required
      ds2[p] = t2;
    }
  }
}

// ---------------------------------------------------------------------------
// Dispatch 2: per-block partial dot over the packed 36-tile layout.
// Each partial = NT*64 = 2304 float4. Block owns 16 float4 slots; thread
// (s = tid&15, pg = tid>>4) sums partials p = pg + 16*i. Diagonal sub-tiles
// (packed indices {0,8,15,21,26,30,33,35}) weight 1, off-diagonal weight 2.
// ---------------------------------------------------------------------------
__global__ __launch_bounds__(256)
void dot_kernel(const float* __restrict__ apart, const float* __restrict__ bpart,
                double* __restrict__ prod)
{
  const int tid = threadIdx.x;
  const int s = tid & 15;          // float4 slot within this block's 16
  const int pg = tid >> 4;         // p-group 0..15
  const f32x4* __restrict__ a4 = (const f32x4*)apart;
  const f32x4* __restrict__ b4 = (const f32x4*)bpart;
  const int base = blockIdx.x * 16 + s;   // f4 index within a partial [0,2304)

  f32x4 sa = {0.f, 0.f, 0.f, 0.f}, sb = {0.f, 0.f, 0.f, 0.f};
#pragma unroll
  for (int i = 0; i < 8; ++i) {
    const int p = pg + (i << 4);
    sa += a4[(size_t)p * (NT * 64) + base];
    sb += b4[(size_t)p * (NT * 64) + base];
  }

  __shared__ f32x4 sA[16][16], sB[16][16];
  sA[pg][s] = sa;
  sB[pg][s] = sb;
  __syncthreads();

  if (tid < 16) {
    f32x4 ta = sA[0][tid], tb = sB[0][tid];
#pragma unroll
    for (int g = 1; g < 16; ++g) { ta += sA[g][tid]; tb += sB[g][tid]; }
    const int tile = (blockIdx.x * 16 + tid) >> 6;   // 64 f4 per sub-tile
    const double w = ((0xA44208101ULL >> tile) & 1) ? 1.0 : 2.0;
    double pr = w * ((double)ta[0] * (double)tb[0]
                   + (double)ta[1] * (double)tb[1]
                   + (double)ta[2] * (double)tb[2]
                   + (double)ta[3] * (double)tb[3]);
    pr += __shfl_down(pr, 8, 16);
    pr += __shfl_down(pr, 4, 16);
    pr += __shfl_down(pr, 2, 16);
    pr += __shfl_down(pr, 1, 16);
    if (tid == 0) prod[blockIdx.x] = pr;   // plain store
  }
}

// ---------------------------------------------------------------------------
// Dispatch 3: one block reduces 144 prods + 128 ds1/ds2 slots (double) and
// writes loss = (S - s2)/(N(N-1)) - (2/N)*s1.
// ---------------------------------------------------------------------------
__global__ __launch_bounds__(256)
void finish_kernel(const double* __restrict__ prod,
                   const double* __restrict__ ds1, const double* __restrict__ ds2,
                   float* __restrict__ out, int N)
{
  const int tid = threadIdx.x;
  const int wv = tid >> 6, lane = tid & 63;
  __shared__ double red[4][3];

  double S = (tid < (NT * 64 * 4) / 64) ? prod[tid] : 0.0;   // 144 entries
  double t1 = (tid < PP) ? ds1[tid] : 0.0;    // 128 entries
  double t2 = (tid < PP) ? ds2[tid] : 0.0;
#pragma unroll
  for (int off = 32; off > 0; off >>= 1) {
    S  += __shfl_down(S, off, 64);
    t1 += __shfl_down(t1, off, 64);
    t2 += __shfl_down(t2, off, 64);
  }
  if (lane == 0) { red[wv][0] = S; red[wv][1] = t1; red[wv][2] = t2; }
  __syncthreads();
  if (tid == 0) {
    double Sf = red[0][0] + red[1][0] + red[2][0] + red[3][0];
    double d1 = red[0][1] + red[1][1] + red[2][1] + red[3][1];
    double d2 = red[0][2] + red[1][2] + red[2][2] + red[3][2];
    double loss = (Sf - d2) / ((double)N * (double)(N - 1)) - (2.0 / N) * d1;
    out[0] = (float)loss;
  }
}

extern "C" void kernel_launch(void* const* d_in, const int* in_sizes, int n_in,
                              void* d_out, int out_size, void* d_ws, size_t ws_size,
                              hipStream_t stream) {
  const float* x = (const float*)d_in[0];
  const float* y = (const float*)d_in[1];
  float* out = (float*)d_out;
  const int N = in_sizes[0] / DD;  // 8192

  char* w = (char*)d_ws;
  float* apart = (float*)w;                              w += (size_t)PP * NT * 256 * 4;
  float* bpart = (float*)w;                              w += (size_t)PP * NT * 256 * 4;
  double* ds1  = (double*)w;                             w += PP * 8;
  double* ds2  = (double*)w;                             w += PP * 8;
  double* prod = (double*)w;

  gram_kernel<<<NB, 512, 0, stream>>>(x, y, apart, bpart, ds1, ds2, N);
  dot_kernel<<<(NT * 64) / 16, 256, 0, stream>>>(apart, bpart, prod);  // 144 blocks
  finish_kernel<<<1, 256, 0, stream>>>(prod, ds1, ds2, out, N);
}